// Round 6
// baseline (270.790 us; speedup 1.0000x reference)
//
#include <hip/hip_runtime.h>

#define NB 8
#define CC 3
#define HH 720
#define WW 1280
#define EPSL 1e-6f
#define HSEG 20            // 720 = 36*20
#define NSEG (HH / HSEG)   // 36
#define G4   (NSEG / 4)    // 9 groups of 4 hsegs (one per wave)
#define OUTC 56            // output cols per wave (64 lanes - 8 halo)
#define NSTRIP 23          // 23*56 = 1288 >= 1280
#define NITER (HSEG + 8)   // 28
#define NPAIR (NB / 2)     // 4 batch-pairs: stream A = n, stream B = n+4
#define NBLK (NPAIR * NSTRIP * G4)  // 828 blocks, 4 waves each

__device__ __forceinline__ float bperm(int addr, float x) {
    return __int_as_float(__builtin_amdgcn_ds_bpermute(addr, __float_as_int(x)));
}

// ---- per-stream macros (S = A or B), all state in suffixed scalars ----

#define DECLS(S) \
    float4 rg1##S = make_float4(0.f,0.f,0.f,0.f); \
    float4 rg2##S=rg1##S, rg3##S=rg1##S, rg4##S=rg1##S, rg5##S=rg1##S, \
           rg6##S=rg1##S, rg7##S=rg1##S, rg8##S=rg1##S; \
    float q1a##S=0,q1b##S=0,q1c##S=0, q2a##S=0,q2b##S=0,q2c##S=0; \
    float q3a##S=0,q3b##S=0,q3c##S=0, q4a##S=0,q4b##S=0,q4c##S=0; \
    float4 vsum##S = make_float4(0.f,0.f,0.f,0.f); \
    float al##S##0, al##S##1, al##S##2, bl##S##0, bl##S##1, bl##S##2; \
    float dB##S, aw##S##0, aw##S##1; \
    float ag##S##00, ag##S##01, ag##S##10, ag##S##11, ag##S##20, ag##S##21;

#define GATH(S, rbase, dv, w0_, w1_, g00_,g01_,g10_,g11_,g20_,g21_) do { \
    float ix_ = gcf - (dv); float x0f_ = floorf(ix_); float wx_ = ix_ - x0f_; \
    int x0i_ = (int)x0f_; int x1i_ = x0i_ + 1; \
    float v0_ = (x0i_ >= 0 && x0i_ < WW) ? 1.f : 0.f; \
    float v1_ = (x1i_ >= 0 && x1i_ < WW) ? 1.f : 0.f; \
    int i0_ = min(max(x0i_,0),WW-1); int i1_ = min(max(x1i_,0),WW-1); \
    w0_ = v0_*(1.f-wx_); w1_ = v1_*wx_; \
    g00_ = rp##S##0[(rbase)+i0_]; g01_ = rp##S##0[(rbase)+i1_]; \
    g10_ = rp##S##1[(rbase)+i0_]; g11_ = rp##S##1[(rbase)+i1_]; \
    g20_ = rp##S##2[(rbase)+i0_]; g21_ = rp##S##2[(rbase)+i1_]; } while(0)

#define PROLOGUE(S) do { \
    float dA_ = dp##S[oP0]; \
    al##S##0 = lp##S##0[oP0]; al##S##1 = lp##S##1[oP0]; al##S##2 = lp##S##2[oP0]; \
    dB##S = dp##S[oP1]; \
    bl##S##0 = lp##S##0[oP1]; bl##S##1 = lp##S##1[oP1]; bl##S##2 = lp##S##2[oP1]; \
    GATH(S, rbP, dA_, aw##S##0, aw##S##1, \
         ag##S##00, ag##S##01, ag##S##10, ag##S##11, ag##S##20, ag##S##21); \
} while(0)

// issue loads for row r+2 (packet C) and left reload for output row r-4
#define LOADS(S) \
    float dC##S = dp##S[o2]; \
    float cl##S##0 = lp##S##0[o2], cl##S##1 = lp##S##1[o2], cl##S##2 = lp##S##2[o2]; \
    float ol##S##0 = lp##S##0[oo], ol##S##1 = lp##S##1[oo], ol##S##2 = lp##S##2[oo];

#define GATHB(S) \
    float bw##S##0, bw##S##1; \
    float bg##S##00, bg##S##01, bg##S##10, bg##S##11, bg##S##20, bg##S##21; \
    GATH(S, rb1, dB##S, bw##S##0, bw##S##1, \
         bg##S##00, bg##S##01, bg##S##10, bg##S##11, bg##S##20, bg##S##21);

#define COMBINE(S) \
    float rca##S = ag##S##00*aw##S##0 + ag##S##01*aw##S##1; \
    float rcb##S = ag##S##10*aw##S##0 + ag##S##11*aw##S##1; \
    float rcc##S = ag##S##20*aw##S##0 + ag##S##21*aw##S##1; \
    float rx##S = al##S##0 + al##S##1 + al##S##2; \
    float ry##S = al##S##0*al##S##0 + al##S##1*al##S##1 + al##S##2*al##S##2; \
    float rz##S = rca##S + rcb##S + rcc##S; \
    float rw##S = rca##S*rca##S + rcb##S*rcb##S + rcc##S*rcc##S; \
    rx##S = valr ? rx##S : 0.f; ry##S = valr ? ry##S : 0.f; \
    rz##S = valr ? rz##S : 0.f; rw##S = valr ? rw##S : 0.f;

#define TREE1(S) \
    float sx##S = bperm(a_m1,rx##S) + rx##S + bperm(a_p1,rx##S); \
    float sy##S = bperm(a_m1,ry##S) + ry##S + bperm(a_p1,ry##S); \
    float sz##S = bperm(a_m1,rz##S) + rz##S + bperm(a_p1,rz##S); \
    float sw##S = bperm(a_m1,rw##S) + rw##S + bperm(a_p1,rw##S);

#define TREE2(S) \
    float hx##S = bperm(a_m3,sx##S) + sx##S + bperm(a_p3,sx##S); \
    float hy##S = bperm(a_m3,sy##S) + sy##S + bperm(a_p3,sy##S); \
    float hz##S = bperm(a_m3,sz##S) + sz##S + bperm(a_p3,sz##S); \
    float hw##S = bperm(a_m3,sw##S) + sw##S + bperm(a_p3,sw##S);

#define ACCUM(S) \
    vsum##S.x += hx##S; vsum##S.y += hy##S; vsum##S.z += hz##S; vsum##S.w += hw##S;

#define OUTP(S) do { \
    float ml_  = vsum##S.x * (1.f/81.f); \
    float msl_ = vsum##S.y * (1.f/81.f); \
    float stdl_ = (msl_ - ml_*ml_) * (81.f/80.f); \
    float sl_ = stdl_ + EPSL; \
    float invl_ = __builtin_amdgcn_rcpf(sl_); \
    invl_ = invl_ * __builtin_fmaf(-sl_, invl_, 2.f); \
    float mr_  = vsum##S.z * (1.f/81.f); \
    float msr_ = vsum##S.w * (1.f/81.f); \
    float stdr_ = (msr_ - mr_*mr_) * (81.f/80.f); \
    float sr_ = stdr_ + EPSL; \
    float invr_ = __builtin_amdgcn_rcpf(sr_); \
    invr_ = invr_ * __builtin_fmaf(-sr_, invr_, 2.f); \
    if (out_lane) { \
        float av_, bv_; \
        av_ = (ol##S##0 - ml_)*invl_; bv_ = (q4a##S - mr_)*invr_; \
        acc += fabsf((av_-bv_)*stdl_); \
        av_ = (ol##S##1 - ml_)*invl_; bv_ = (q4b##S - mr_)*invr_; \
        acc += fabsf((av_-bv_)*stdl_); \
        av_ = (ol##S##2 - ml_)*invl_; bv_ = (q4c##S - mr_)*invr_; \
        acc += fabsf((av_-bv_)*stdl_); \
    } \
    vsum##S.x -= rg8##S.x; vsum##S.y -= rg8##S.y; \
    vsum##S.z -= rg8##S.z; vsum##S.w -= rg8##S.w; \
} while(0)

#define SHIFT(S) \
    rg8##S = rg7##S; rg7##S = rg6##S; rg6##S = rg5##S; rg5##S = rg4##S; \
    rg4##S = rg3##S; rg3##S = rg2##S; rg2##S = rg1##S; \
    rg1##S = make_float4(hx##S, hy##S, hz##S, hw##S); \
    q4a##S=q3a##S; q4b##S=q3b##S; q4c##S=q3c##S; \
    q3a##S=q2a##S; q3b##S=q2b##S; q3c##S=q2c##S; \
    q2a##S=q1a##S; q2b##S=q1b##S; q2c##S=q1c##S; \
    q1a##S=rca##S; q1b##S=rcb##S; q1c##S=rcc##S; \
    al##S##0=bl##S##0; al##S##1=bl##S##1; al##S##2=bl##S##2; \
    aw##S##0=bw##S##0; aw##S##1=bw##S##1; \
    ag##S##00=bg##S##00; ag##S##01=bg##S##01; ag##S##10=bg##S##10; \
    ag##S##11=bg##S##11; ag##S##20=bg##S##20; ag##S##21=bg##S##21; \
    dB##S=dC##S; bl##S##0=cl##S##0; bl##S##1=cl##S##1; bl##S##2=cl##S##2;

__global__ __launch_bounds__(256)
void fused_loss_kernel(const float* __restrict__ left,
                       const float* __restrict__ right,
                       const float* __restrict__ disp,
                       float* __restrict__ out)
{
    const int t    = threadIdx.x;
    const int lane = t & 63;
    const int wid  = t >> 6;

    // block-scalar decode: batch-pair and strip uniform per block
    const int b     = blockIdx.x;
    const int strip = b % NSTRIP;
    const int g     = (b / NSTRIP) % G4;
    const int np    = b / (NSTRIP * G4);      // batch pair: (np, np+4)

    const int h0 = (g * 4 + wid) * HSEG;      // per-wave segment
    const int gc  = strip * OUTC + lane - 4;
    const int gcc = min(max(gc, 0), WW - 1);
    const float gcf = (float)gc;
    const bool col_ok   = (gc >= 0) && (gc < WW);
    const bool out_lane = (lane >= 4) && (lane < 4 + OUTC) && (gc < WW);

    // scalar (SGPR) base pointers, streams A (n=np) and B (n=np+4)
    const size_t plane = (size_t)HH * WW;
    const float* __restrict__ dpA  = disp  + (size_t)np * plane;
    const float* __restrict__ lpA0 = left  + (size_t)np * CC * plane;
    const float* __restrict__ lpA1 = lpA0 + plane;
    const float* __restrict__ lpA2 = lpA1 + plane;
    const float* __restrict__ rpA0 = right + (size_t)np * CC * plane;
    const float* __restrict__ rpA1 = rpA0 + plane;
    const float* __restrict__ rpA2 = rpA1 + plane;
    const float* __restrict__ dpB  = dpA  + (size_t)NPAIR * plane;
    const float* __restrict__ lpB0 = lpA0 + (size_t)NPAIR * CC * plane;
    const float* __restrict__ lpB1 = lpB0 + plane;
    const float* __restrict__ lpB2 = lpB1 + plane;
    const float* __restrict__ rpB0 = rpA0 + (size_t)NPAIR * CC * plane;
    const float* __restrict__ rpB1 = rpB0 + plane;
    const float* __restrict__ rpB2 = rpB1 + plane;

    // hoisted bpermute byte-addresses
    const int a_m1 = ((lane + 63) & 63) << 2;
    const int a_p1 = ((lane +  1) & 63) << 2;
    const int a_m3 = ((lane + 61) & 63) << 2;
    const int a_p3 = ((lane +  3) & 63) << 2;

    DECLS(A)
    DECLS(B)

    const int r0 = h0 - 4;

    // ---- prologue: rows r0 and r0+1, shared offsets ----
    const unsigned oP0 = (unsigned)(min(max(r0,     0), HH - 1) * WW) + gcc;
    const unsigned oP1 = (unsigned)(min(max(r0 + 1, 0), HH - 1) * WW) + gcc;
    const unsigned rbP = (unsigned)(min(max(r0,     0), HH - 1) * WW);
    PROLOGUE(A);
    PROLOGUE(B);

    float acc = 0.f;

    for (int iter = 0; iter < NITER; ++iter) {
        const int r = r0 + iter;
        // shared per-iter offsets (identical for both streams)
        const unsigned o2  = (unsigned)(min(max(r + 2, 0), HH - 1) * WW) + gcc;
        const unsigned oo  = (unsigned)(min(max(r - 4, 0), HH - 1) * WW) + gcc;
        const unsigned rb1 = (unsigned)(min(max(r + 1, 0), HH - 1) * WW);
        const bool valr = col_ok && ((unsigned)r < (unsigned)HH);

        LOADS(A)  LOADS(B)          // next-row packets + left reloads
        GATHB(A)  GATHB(B)          // divergent gathers for r+1
        COMBINE(A) COMBINE(B)       // raw sums for row r
        TREE1(A)  TREE1(B)          // 16 bpermutes, one lgkm wait
        TREE2(A)  TREE2(B)          // 16 bpermutes, one lgkm wait
        ACCUM(A)  ACCUM(B)
        if (iter >= 8) { OUTP(A); OUTP(B); }
        SHIFT(A)  SHIFT(B)
    }

    // ---- reduction: wave shuffle -> LDS (4 slots) -> atomic ----
#pragma unroll
    for (int off = 32; off > 0; off >>= 1)
        acc += __shfl_down(acc, off, 64);
    __shared__ float red[4];
    if (lane == 0) red[wid] = acc;
    __syncthreads();
    if (t == 0) {
        float s = red[0] + red[1] + red[2] + red[3];
        const float inv_count = 1.f / ((float)NB * CC * HH * WW);
        atomicAdd(out, s * inv_count);
    }
}

extern "C" void kernel_launch(void* const* d_in, const int* in_sizes, int n_in,
                              void* d_out, int out_size, void* d_ws, size_t ws_size,
                              hipStream_t stream) {
    const float* left  = (const float*)d_in[0];
    const float* right = (const float*)d_in[1];
    const float* disp  = (const float*)d_in[2];
    float* out = (float*)d_out;

    hipMemsetAsync(out, 0, sizeof(float) * out_size, stream);

    hipLaunchKernelGGL(fused_loss_kernel, dim3(NBLK), dim3(256), 0, stream,
                       left, right, disp, out);
}